// Round 14
// baseline (280.103 us; speedup 1.0000x reference)
//
#include <hip/hip_runtime.h>

#define BN_EPS 1e-5f

typedef __attribute__((ext_vector_type(8))) short short8;
typedef __attribute__((ext_vector_type(4))) float floatx4;

#define GLL(gp, lp)                                                            \
    __builtin_amdgcn_global_load_lds(                                          \
        (const __attribute__((address_space(1))) void*)(gp),                   \
        (__attribute__((address_space(3))) void*)(lp), 16, 0, 0)

__device__ inline unsigned short f2bf(float f) {
    unsigned int u = __float_as_uint(f);
    unsigned int r = (u + 0x7FFF + ((u >> 16) & 1)) >> 16;  // RNE
    return (unsigned short)r;
}

__device__ inline float bf2f(unsigned short u) {
    return __uint_as_float(((unsigned int)u) << 16);
}

// ---------------- prep: count in-degree + fp32->bf16 casts (merged) --------

__global__ void prep_kernel(const int* __restrict__ col, int* __restrict__ cnt,
                            const float* __restrict__ x, const float* __restrict__ W1,
                            const float* __restrict__ W2, ushort* __restrict__ xbf,
                            ushort* __restrict__ W1bf, ushort* __restrict__ W2bf,
                            int E, int n4x, int n4w) {
    int i = blockIdx.x * blockDim.x + threadIdx.x;
    if (i < E) {
        atomicAdd(&cnt[col[i]], 1);
        return;
    }
    int j = i - E;
    const float* src;
    ushort* dst;
    if (j < n4x) { src = x; dst = xbf; }
    else if (j < n4x + n4w) { src = W1; dst = W1bf; j -= n4x; }
    else if (j < n4x + 2 * n4w) { src = W2; dst = W2bf; j -= n4x + n4w; }
    else return;
    float4 v = ((const float4*)src)[j];
    ushort4 o;
    o.x = f2bf(v.x); o.y = f2bf(v.y); o.z = f2bf(v.z); o.w = f2bf(v.w);
    ((ushort4*)dst)[j] = o;
}

// single-block scan over N counts -> rowptr/cursor; also computes dis.
__global__ __launch_bounds__(1024) void scan_dis_kernel(
    const int* __restrict__ cnt, float* __restrict__ dis,
    int* __restrict__ rowptr, int* __restrict__ cursor, int N) {
    __shared__ int sums[1024];
    int t = threadIdx.x;
    int per = (N + 1023) / 1024;
    int start = t * per;
    int local = 0;
    for (int i = 0; i < per; i++) {
        int idx = start + i;
        if (idx < N) {
            int cv = cnt[idx];
            local += cv;
            dis[idx] = rsqrtf((float)(cv + 1));   // +1 self loop
        }
    }
    sums[t] = local;
    __syncthreads();
    for (int off = 1; off < 1024; off <<= 1) {
        int v = (t >= off) ? sums[t - off] : 0;
        __syncthreads();
        sums[t] += v;
        __syncthreads();
    }
    int run = (t == 0) ? 0 : sums[t - 1];
    for (int i = 0; i < per; i++) {
        int idx = start + i;
        if (idx < N) {
            rowptr[idx] = run;
            cursor[idx] = run;
            run += cnt[idx];
        }
    }
    if (t == 0) rowptr[N] = sums[1023];
}

__global__ void scatter_kernel(const int* __restrict__ row, const int* __restrict__ col,
                               int* __restrict__ cursor, int* __restrict__ adj, int E) {
    int e = blockIdx.x * blockDim.x + threadIdx.x;
    if (e < E) {
        int pos = atomicAdd(&cursor[col[e]], 1);
        adj[pos] = row[e];
    }
}

// ---------------- MFMA GEMM: C[M,N] = A[M,K] @ B[N,K]^T (bf16 in) ----------
// STATS: epilogue emits per-column partial sum/sumsq (fp32 acc) into
// psum[blockIdx.y * N + col]  (layout [chunk][col], coalesced both ways).

template <bool OUT_BF16, bool STATS>
__global__ __launch_bounds__(256) void gemm_mfma_kernel(
    const ushort* __restrict__ A, const ushort* __restrict__ B,
    void* __restrict__ Cout, float* __restrict__ psum, float* __restrict__ psumsq,
    int M, int N, int K) {
    __shared__ ushort As[128 * 32];
    __shared__ ushort Bs[128 * 32];
    int tid = threadIdx.x;
    int wave = tid >> 6;
    int lane = tid & 63;
    int quad = lane >> 4;
    int l15 = lane & 15;
    int m0 = blockIdx.y * 128;
    int n0 = blockIdx.x * 128;

    int srow = lane >> 2;
    int skoff = (lane & 3) * 8;

    floatx4 acc[4][4];
#pragma unroll
    for (int i = 0; i < 4; i++)
#pragma unroll
        for (int j = 0; j < 4; j++) acc[i][j] = (floatx4){0.f, 0.f, 0.f, 0.f};

    int wm = (wave & 1) * 64;
    int wn = (wave >> 1) * 64;

    for (int k0 = 0; k0 < K; k0 += 32) {
#pragma unroll
        for (int cc = 0; cc < 2; cc++) {
            int c = wave * 2 + cc;
            int arow = m0 + c * 16 + srow;
            arow = min(arow, M - 1);
            const ushort* ga = A + (size_t)arow * K + k0 + skoff;
            GLL(ga, (char*)As + c * 1024);
            int brow = n0 + c * 16 + srow;
            const ushort* gb = B + (size_t)brow * K + k0 + skoff;
            GLL(gb, (char*)Bs + c * 1024);
        }
        __syncthreads();

        short8 af[4], bfr[4];
#pragma unroll
        for (int i = 0; i < 4; i++) {
            int r = wm + i * 16 + l15;
            af[i] = *(const short8*)(As + r * 32 + quad * 8);
        }
#pragma unroll
        for (int j = 0; j < 4; j++) {
            int r = wn + j * 16 + l15;
            bfr[j] = *(const short8*)(Bs + r * 32 + quad * 8);
        }
#pragma unroll
        for (int i = 0; i < 4; i++)
#pragma unroll
            for (int j = 0; j < 4; j++)
                acc[i][j] = __builtin_amdgcn_mfma_f32_16x16x32_bf16(af[i], bfr[j], acc[i][j], 0, 0, 0);
        __syncthreads();
    }

#pragma unroll
    for (int i = 0; i < 4; i++) {
#pragma unroll
        for (int r = 0; r < 4; r++) {
            int row = m0 + wm + i * 16 + quad * 4 + r;
            if (row < M) {
                if (OUT_BF16) {
                    ushort* cp = (ushort*)Cout + (size_t)row * N + n0 + wn + l15;
#pragma unroll
                    for (int j = 0; j < 4; j++) cp[j * 16] = f2bf(acc[i][j][r]);
                } else {
                    float* cp = (float*)Cout + (size_t)row * N + n0 + wn + l15;
#pragma unroll
                    for (int j = 0; j < 4; j++) cp[j * 16] = acc[i][j][r];
                }
            }
        }
    }

    if (STATS) {
        float s[4] = {0.f, 0.f, 0.f, 0.f};
        float q[4] = {0.f, 0.f, 0.f, 0.f};
#pragma unroll
        for (int i = 0; i < 4; i++) {
#pragma unroll
            for (int r = 0; r < 4; r++) {
                if (m0 + wm + i * 16 + quad * 4 + r < M) {
#pragma unroll
                    for (int j = 0; j < 4; j++) {
                        float v = acc[i][j][r];
                        s[j] += v;
                        q[j] += v * v;
                    }
                }
            }
        }
#pragma unroll
        for (int j = 0; j < 4; j++) {
            s[j] += __shfl_xor(s[j], 16, 64);
            s[j] += __shfl_xor(s[j], 32, 64);
            q[j] += __shfl_xor(q[j], 16, 64);
            q[j] += __shfl_xor(q[j], 32, 64);
        }
        __shared__ float sArr[4][64];
        __shared__ float qArr[4][64];
        if (quad == 0) {
#pragma unroll
            for (int j = 0; j < 4; j++) {
                sArr[wave][j * 16 + l15] = s[j];
                qArr[wave][j * 16 + l15] = q[j];
            }
        }
        __syncthreads();
        if (tid < 128) {
            int half = tid >> 6;
            int cc = tid & 63;
            float ss = sArr[half * 2][cc] + sArr[half * 2 + 1][cc];
            float qq = qArr[half * 2][cc] + qArr[half * 2 + 1][cc];
            int colI = n0 + half * 64 + cc;
            psum[(size_t)blockIdx.y * N + colI] = ss;
            psumsq[(size_t)blockIdx.y * N + colI] = qq;
        }
    }
}

// ---------------- bf16 gather, C=256 channels ----------------
// STATS: wave 0 additionally atomicAdds the node's row into chunked
// accumulators psum/psumsq[chunk=v&(SCH-1)][256] (zeroed by host memset).

template <bool OUT_BF16, bool STATS>
__global__ __launch_bounds__(256) void gather_bf_kernel(
    const ushort* __restrict__ xl, const int* __restrict__ rowptr,
    const int* __restrict__ adj, const float* __restrict__ dis,
    void* __restrict__ h, float* __restrict__ psum, float* __restrict__ psumsq,
    int schunks) {
    int v = blockIdx.x;
    int wave = threadIdx.x >> 6;
    int lane = threadIdx.x & 63;
    float dv = dis[v];

    float acc[4] = {0.f, 0.f, 0.f, 0.f};
    int e0 = rowptr[v], e1 = rowptr[v + 1];
    for (int e = e0 + wave; e < e1; e += 4) {
        int r = adj[e];
        float wgt = dis[r] * dv;
        ushort4 u = ((const ushort4*)xl)[(size_t)r * 64 + lane];
        acc[0] = fmaf(bf2f(u.x), wgt, acc[0]);
        acc[1] = fmaf(bf2f(u.y), wgt, acc[1]);
        acc[2] = fmaf(bf2f(u.z), wgt, acc[2]);
        acc[3] = fmaf(bf2f(u.w), wgt, acc[3]);
    }

    __shared__ float4 red[4][64];
    red[wave][lane] = make_float4(acc[0], acc[1], acc[2], acc[3]);
    __syncthreads();
    if (wave == 0) {
        float4 s = red[0][lane];
        float4 b = red[1][lane];
        float4 c = red[2][lane];
        float4 d = red[3][lane];
        s.x += b.x + c.x + d.x;
        s.y += b.y + c.y + d.y;
        s.z += b.z + c.z + d.z;
        s.w += b.w + c.w + d.w;
        ushort4 u = ((const ushort4*)xl)[(size_t)v * 64 + lane];
        float w2 = dv * dv;
        s.x = fmaf(bf2f(u.x), w2, s.x);
        s.y = fmaf(bf2f(u.y), w2, s.y);
        s.z = fmaf(bf2f(u.z), w2, s.z);
        s.w = fmaf(bf2f(u.w), w2, s.w);
        if (OUT_BF16) {
            ushort4 o;
            o.x = f2bf(s.x); o.y = f2bf(s.y); o.z = f2bf(s.z); o.w = f2bf(s.w);
            ((ushort4*)h)[(size_t)v * 64 + lane] = o;
        } else {
            ((float4*)h)[(size_t)v * 64 + lane] = s;
        }
        if (STATS) {
            int chunk = v & (schunks - 1);
            float* ps = psum + (size_t)chunk * 256 + lane * 4;
            float* qs = psumsq + (size_t)chunk * 256 + lane * 4;
            atomicAdd(ps + 0, s.x);
            atomicAdd(ps + 1, s.y);
            atomicAdd(ps + 2, s.z);
            atomicAdd(ps + 3, s.w);
            atomicAdd(qs + 0, s.x * s.x);
            atomicAdd(qs + 1, s.y * s.y);
            atomicAdd(qs + 2, s.z * s.z);
            atomicAdd(qs + 3, s.w * s.w);
        }
    }
}

// ---------------- fused: redundant reduce1 -> BN1+ReLU+cast stream ----------
// psum layout [chunks][IC]; lane-per-channel coalesced, 4-way ILP accumulators.

__global__ __launch_bounds__(256) void bn_apply_fused_kernel(
    const ushort* __restrict__ h, const float* __restrict__ psum,
    const float* __restrict__ psumsq, const float* __restrict__ gamma,
    const float* __restrict__ beta, ushort* __restrict__ out,
    int N, int IC, int chunks, int n8) {
    __shared__ float sc[512];
    __shared__ float sh[512];
    int t = threadIdx.x;
    float invN = 1.0f / (float)N;
    for (int c = t; c < IC; c += 256) {
        float s0 = 0.f, s1 = 0.f, s2 = 0.f, s3 = 0.f;
        float q0 = 0.f, q1 = 0.f, q2 = 0.f, q3 = 0.f;
        int k = 0;
        for (; k + 3 < chunks; k += 4) {
            s0 += psum[(size_t)(k + 0) * IC + c];
            s1 += psum[(size_t)(k + 1) * IC + c];
            s2 += psum[(size_t)(k + 2) * IC + c];
            s3 += psum[(size_t)(k + 3) * IC + c];
            q0 += psumsq[(size_t)(k + 0) * IC + c];
            q1 += psumsq[(size_t)(k + 1) * IC + c];
            q2 += psumsq[(size_t)(k + 2) * IC + c];
            q3 += psumsq[(size_t)(k + 3) * IC + c];
        }
        for (; k < chunks; k++) {
            s0 += psum[(size_t)k * IC + c];
            q0 += psumsq[(size_t)k * IC + c];
        }
        float s = (s0 + s1) + (s2 + s3);
        float q = (q0 + q1) + (q2 + q3);
        float mean = s * invN;
        float var = q * invN - mean * mean;
        float scv = gamma[c] * rsqrtf(var + BN_EPS);
        sc[c] = scv;
        sh[c] = beta[c] - mean * scv;
    }
    __syncthreads();

    int IC8 = IC >> 3;
    for (int i = blockIdx.x * 256 + t; i < n8; i += gridDim.x * 256) {
        int c8 = (i & (IC8 - 1)) * 8;
        ushort4 a = ((const ushort4*)h)[2 * i];
        ushort4 b = ((const ushort4*)h)[2 * i + 1];
        ushort4 oa, ob;
        oa.x = f2bf(fmaxf(fmaf(bf2f(a.x), sc[c8 + 0], sh[c8 + 0]), 0.f));
        oa.y = f2bf(fmaxf(fmaf(bf2f(a.y), sc[c8 + 1], sh[c8 + 1]), 0.f));
        oa.z = f2bf(fmaxf(fmaf(bf2f(a.z), sc[c8 + 2], sh[c8 + 2]), 0.f));
        oa.w = f2bf(fmaxf(fmaf(bf2f(a.w), sc[c8 + 3], sh[c8 + 3]), 0.f));
        ob.x = f2bf(fmaxf(fmaf(bf2f(b.x), sc[c8 + 4], sh[c8 + 4]), 0.f));
        ob.y = f2bf(fmaxf(fmaf(bf2f(b.y), sc[c8 + 5], sh[c8 + 5]), 0.f));
        ob.z = f2bf(fmaxf(fmaf(bf2f(b.z), sc[c8 + 6], sh[c8 + 6]), 0.f));
        ob.w = f2bf(fmaxf(fmaf(bf2f(b.w), sc[c8 + 7], sh[c8 + 7]), 0.f));
        ((ushort4*)out)[2 * i] = oa;
        ((ushort4*)out)[2 * i + 1] = ob;
    }
}

// ---------------- fused: redundant reduce2 -> relu(bn2(h2)+x) stream --------
// psum layout [chunks][C], chunks=64; lane-per-channel coalesced reduce.

__global__ __launch_bounds__(256) void final_fused_kernel(
    const float* __restrict__ h2, const float* __restrict__ x,
    const float* __restrict__ psum, const float* __restrict__ psumsq,
    const float* __restrict__ gamma, const float* __restrict__ beta,
    float* __restrict__ out, int N, int C, int chunks, int total4) {
    __shared__ float sc[256];
    __shared__ float sh[256];
    int t = threadIdx.x;
    float invN = 1.0f / (float)N;
    {
        int c = t;  // C == 256 == blockDim
        float s0 = 0.f, s1 = 0.f, s2 = 0.f, s3 = 0.f;
        float q0 = 0.f, q1 = 0.f, q2 = 0.f, q3 = 0.f;
        for (int k = 0; k < chunks; k += 4) {
            s0 += psum[(size_t)(k + 0) * C + c];
            s1 += psum[(size_t)(k + 1) * C + c];
            s2 += psum[(size_t)(k + 2) * C + c];
            s3 += psum[(size_t)(k + 3) * C + c];
            q0 += psumsq[(size_t)(k + 0) * C + c];
            q1 += psumsq[(size_t)(k + 1) * C + c];
            q2 += psumsq[(size_t)(k + 2) * C + c];
            q3 += psumsq[(size_t)(k + 3) * C + c];
        }
        float s = (s0 + s1) + (s2 + s3);
        float q = (q0 + q1) + (q2 + q3);
        float mean = s * invN;
        float var = q * invN - mean * mean;
        float scv = gamma[c] * rsqrtf(var + BN_EPS);
        sc[c] = scv;
        sh[c] = beta[c] - mean * scv;
    }
    __syncthreads();

    int C4 = C >> 2;
    for (int i = blockIdx.x * 256 + t; i < total4; i += gridDim.x * 256) {
        int c4 = (i & (C4 - 1)) * 4;
        float4 h = ((const float4*)h2)[i];
        float4 xv = ((const float4*)x)[i];
        float4 o;
        o.x = fmaxf(fmaf(h.x, sc[c4 + 0], sh[c4 + 0]) + xv.x, 0.f);
        o.y = fmaxf(fmaf(h.y, sc[c4 + 1], sh[c4 + 1]) + xv.y, 0.f);
        o.z = fmaxf(fmaf(h.z, sc[c4 + 2], sh[c4 + 2]) + xv.z, 0.f);
        o.w = fmaxf(fmaf(h.w, sc[c4 + 3], sh[c4 + 3]) + xv.w, 0.f);
        ((float4*)out)[i] = o;
    }
}

// ---------------- launch ----------------

extern "C" void kernel_launch(void* const* d_in, const int* in_sizes, int n_in,
                              void* d_out, int out_size, void* d_ws, size_t ws_size,
                              hipStream_t stream) {
    const float* x  = (const float*)d_in[0];
    const int*   es = (const int*)d_in[1];
    const float* W1 = (const float*)d_in[2];
    const float* g1 = (const float*)d_in[3];
    const float* b1 = (const float*)d_in[4];
    const float* W2 = (const float*)d_in[5];
    const float* g2 = (const float*)d_in[6];
    const float* b2 = (const float*)d_in[7];
    float* out = (float*)d_out;

    const int E  = in_sizes[1] / 2;
    const int IC = in_sizes[3];   // 512
    const int C  = in_sizes[7];   // 256
    const int N  = in_sizes[0] / C;
    const int MTILES = (N + 127) / 128;   // 79
    const int SCH2 = 64;                  // BN2 atomic chunks

    const int* row = es;
    const int* col = es + E;

    // ---- workspace layout (cnt + psum2 + psumsq2 first: one memset) ----
    char* w = (char*)d_ws;
    size_t off = 0;
    auto alloc = [&](size_t bytes) -> void* {
        void* p = w + off;
        off = (off + bytes + 255) & ~(size_t)255;
        return p;
    };
    size_t zero_begin = off;
    int*   cnt     = (int*)alloc((size_t)N * 4);
    float* psum2   = (float*)alloc((size_t)SCH2 * C * 4);
    float* psumsq2 = (float*)alloc((size_t)SCH2 * C * 4);
    size_t zero_end = off;
    float* dis     = (float*)alloc((size_t)N * 4);
    int*   rowptr  = (int*)alloc((size_t)(N + 1) * 4);
    int*   cursor  = (int*)alloc((size_t)N * 4);
    int*   adj     = (int*)alloc((size_t)E * 4);
    float* psum1   = (float*)alloc((size_t)MTILES * IC * 4);
    float* psumsq1 = (float*)alloc((size_t)MTILES * IC * 4);
    ushort* xbf    = (ushort*)alloc((size_t)N * C * 2);
    ushort* W1bf   = (ushort*)alloc((size_t)IC * C * 2);
    ushort* W2bf   = (ushort*)alloc((size_t)IC * C * 2);
    ushort* g1x    = (ushort*)alloc((size_t)N * C * 2);
    ushort* h1raw  = (ushort*)alloc((size_t)N * IC * 2);  // GEMM1 out, bf16
    ushort* h1bf   = (ushort*)alloc((size_t)N * IC * 2);  // BN1+ReLU out
    ushort* xl2bf  = (ushort*)alloc((size_t)N * C * 2);
    float*  h2     = (float*)alloc((size_t)N * C * 4);

    hipMemsetAsync(w + zero_begin, 0, zero_end - zero_begin, stream);

    // ---- prep: degree count + bf16 casts ----
    {
        int n4x = N * C / 4, n4w = IC * C / 4;
        int tot = E + n4x + 2 * n4w;
        prep_kernel<<<(tot + 255) / 256, 256, 0, stream>>>(
            col, cnt, x, W1, W2, xbf, W1bf, W2bf, E, n4x, n4w);
    }
    scan_dis_kernel<<<1, 1024, 0, stream>>>(cnt, dis, rowptr, cursor, N);
    scatter_kernel<<<(E + 255) / 256, 256, 0, stream>>>(row, col, cursor, adj, E);

    // ---- layer 1: g1x = A_norm(x); h1raw = g1x @ W1^T (bf16 + stats1) ----
    gather_bf_kernel<true, false><<<N, 256, 0, stream>>>(
        xbf, rowptr, adj, dis, g1x, nullptr, nullptr, 0);
    {
        dim3 grid(IC / 128, MTILES);
        gemm_mfma_kernel<true, true><<<grid, 256, 0, stream>>>(
            g1x, W1bf, h1raw, psum1, psumsq1, N, IC, C);
    }
    // fused reduce1 + BN1 + ReLU + cast
    bn_apply_fused_kernel<<<640, 256, 0, stream>>>(
        h1raw, psum1, psumsq1, g1, b1, h1bf, N, IC, MTILES, N * IC / 8);

    // ---- layer 2: xl2 = h1bf @ W2^T (bf16); h2 = A_norm(xl2) + atomic stats2 --
    {
        dim3 grid(C / 128, MTILES);
        gemm_mfma_kernel<true, false><<<grid, 256, 0, stream>>>(
            h1bf, W2bf, xl2bf, nullptr, nullptr, N, C, IC);
    }
    gather_bf_kernel<false, true><<<N, 256, 0, stream>>>(
        xl2bf, rowptr, adj, dis, h2, psum2, psumsq2, SCH2);

    // ---- fused reduce2 + relu(bn2(h2) + x) ----
    final_fused_kernel<<<1250, 256, 0, stream>>>(
        h2, x, psum2, psumsq2, g2, b2, out, N, C, SCH2, N * C / 4);
}

// Round 15
// 236.009 us; speedup vs baseline: 1.1868x; 1.1868x over previous
//
#include <hip/hip_runtime.h>

#define BN_EPS 1e-5f

typedef __attribute__((ext_vector_type(8))) short short8;
typedef __attribute__((ext_vector_type(4))) float floatx4;

#define GLL(gp, lp)                                                            \
    __builtin_amdgcn_global_load_lds(                                          \
        (const __attribute__((address_space(1))) void*)(gp),                   \
        (__attribute__((address_space(3))) void*)(lp), 16, 0, 0)

__device__ inline unsigned short f2bf(float f) {
    unsigned int u = __float_as_uint(f);
    unsigned int r = (u + 0x7FFF + ((u >> 16) & 1)) >> 16;  // RNE
    return (unsigned short)r;
}

__device__ inline float bf2f(unsigned short u) {
    return __uint_as_float(((unsigned int)u) << 16);
}

// ---------------- prep: count in-degree + fp32->bf16 casts (merged) --------

__global__ void prep_kernel(const int* __restrict__ col, int* __restrict__ cnt,
                            const float* __restrict__ x, const float* __restrict__ W1,
                            const float* __restrict__ W2, ushort* __restrict__ xbf,
                            ushort* __restrict__ W1bf, ushort* __restrict__ W2bf,
                            int E, int n4x, int n4w) {
    int i = blockIdx.x * blockDim.x + threadIdx.x;
    if (i < E) {
        atomicAdd(&cnt[col[i]], 1);
        return;
    }
    int j = i - E;
    const float* src;
    ushort* dst;
    if (j < n4x) { src = x; dst = xbf; }
    else if (j < n4x + n4w) { src = W1; dst = W1bf; j -= n4x; }
    else if (j < n4x + 2 * n4w) { src = W2; dst = W2bf; j -= n4x + n4w; }
    else return;
    float4 v = ((const float4*)src)[j];
    ushort4 o;
    o.x = f2bf(v.x); o.y = f2bf(v.y); o.z = f2bf(v.z); o.w = f2bf(v.w);
    ((ushort4*)dst)[j] = o;
}

// single-block scan over N counts -> rowptr/cursor; also computes dis.
__global__ __launch_bounds__(1024) void scan_dis_kernel(
    const int* __restrict__ cnt, float* __restrict__ dis,
    int* __restrict__ rowptr, int* __restrict__ cursor, int N) {
    __shared__ int sums[1024];
    int t = threadIdx.x;
    int per = (N + 1023) / 1024;
    int start = t * per;
    int local = 0;
    for (int i = 0; i < per; i++) {
        int idx = start + i;
        if (idx < N) {
            int cv = cnt[idx];
            local += cv;
            dis[idx] = rsqrtf((float)(cv + 1));   // +1 self loop
        }
    }
    sums[t] = local;
    __syncthreads();
    for (int off = 1; off < 1024; off <<= 1) {
        int v = (t >= off) ? sums[t - off] : 0;
        __syncthreads();
        sums[t] += v;
        __syncthreads();
    }
    int run = (t == 0) ? 0 : sums[t - 1];
    for (int i = 0; i < per; i++) {
        int idx = start + i;
        if (idx < N) {
            rowptr[idx] = run;
            cursor[idx] = run;
            run += cnt[idx];
        }
    }
    if (t == 0) rowptr[N] = sums[1023];
}

__global__ void scatter_kernel(const int* __restrict__ row, const int* __restrict__ col,
                               int* __restrict__ cursor, int* __restrict__ adj, int E) {
    int e = blockIdx.x * blockDim.x + threadIdx.x;
    if (e < E) {
        int pos = atomicAdd(&cursor[col[e]], 1);
        adj[pos] = row[e];
    }
}

// ---------------- MFMA GEMM: C[M,N] = A[M,K] @ B[N,K]^T (bf16 in) ----------
// STATS: epilogue emits per-column partial sum/sumsq (fp32 acc) into
// psum[blockIdx.y * N + col]  (layout [chunk][col], coalesced both ways).

template <bool OUT_BF16, bool STATS>
__global__ __launch_bounds__(256) void gemm_mfma_kernel(
    const ushort* __restrict__ A, const ushort* __restrict__ B,
    void* __restrict__ Cout, float* __restrict__ psum, float* __restrict__ psumsq,
    int M, int N, int K) {
    __shared__ ushort As[128 * 32];
    __shared__ ushort Bs[128 * 32];
    int tid = threadIdx.x;
    int wave = tid >> 6;
    int lane = tid & 63;
    int quad = lane >> 4;
    int l15 = lane & 15;
    int m0 = blockIdx.y * 128;
    int n0 = blockIdx.x * 128;

    int srow = lane >> 2;
    int skoff = (lane & 3) * 8;

    floatx4 acc[4][4];
#pragma unroll
    for (int i = 0; i < 4; i++)
#pragma unroll
        for (int j = 0; j < 4; j++) acc[i][j] = (floatx4){0.f, 0.f, 0.f, 0.f};

    int wm = (wave & 1) * 64;
    int wn = (wave >> 1) * 64;

    for (int k0 = 0; k0 < K; k0 += 32) {
#pragma unroll
        for (int cc = 0; cc < 2; cc++) {
            int c = wave * 2 + cc;
            int arow = m0 + c * 16 + srow;
            arow = min(arow, M - 1);
            const ushort* ga = A + (size_t)arow * K + k0 + skoff;
            GLL(ga, (char*)As + c * 1024);
            int brow = n0 + c * 16 + srow;
            const ushort* gb = B + (size_t)brow * K + k0 + skoff;
            GLL(gb, (char*)Bs + c * 1024);
        }
        __syncthreads();

        short8 af[4], bfr[4];
#pragma unroll
        for (int i = 0; i < 4; i++) {
            int r = wm + i * 16 + l15;
            af[i] = *(const short8*)(As + r * 32 + quad * 8);
        }
#pragma unroll
        for (int j = 0; j < 4; j++) {
            int r = wn + j * 16 + l15;
            bfr[j] = *(const short8*)(Bs + r * 32 + quad * 8);
        }
#pragma unroll
        for (int i = 0; i < 4; i++)
#pragma unroll
            for (int j = 0; j < 4; j++)
                acc[i][j] = __builtin_amdgcn_mfma_f32_16x16x32_bf16(af[i], bfr[j], acc[i][j], 0, 0, 0);
        __syncthreads();
    }

#pragma unroll
    for (int i = 0; i < 4; i++) {
#pragma unroll
        for (int r = 0; r < 4; r++) {
            int row = m0 + wm + i * 16 + quad * 4 + r;
            if (row < M) {
                if (OUT_BF16) {
                    ushort* cp = (ushort*)Cout + (size_t)row * N + n0 + wn + l15;
#pragma unroll
                    for (int j = 0; j < 4; j++) cp[j * 16] = f2bf(acc[i][j][r]);
                } else {
                    float* cp = (float*)Cout + (size_t)row * N + n0 + wn + l15;
#pragma unroll
                    for (int j = 0; j < 4; j++) cp[j * 16] = acc[i][j][r];
                }
            }
        }
    }

    if (STATS) {
        float s[4] = {0.f, 0.f, 0.f, 0.f};
        float q[4] = {0.f, 0.f, 0.f, 0.f};
#pragma unroll
        for (int i = 0; i < 4; i++) {
#pragma unroll
            for (int r = 0; r < 4; r++) {
                if (m0 + wm + i * 16 + quad * 4 + r < M) {
#pragma unroll
                    for (int j = 0; j < 4; j++) {
                        float v = acc[i][j][r];
                        s[j] += v;
                        q[j] += v * v;
                    }
                }
            }
        }
#pragma unroll
        for (int j = 0; j < 4; j++) {
            s[j] += __shfl_xor(s[j], 16, 64);
            s[j] += __shfl_xor(s[j], 32, 64);
            q[j] += __shfl_xor(q[j], 16, 64);
            q[j] += __shfl_xor(q[j], 32, 64);
        }
        __shared__ float sArr[4][64];
        __shared__ float qArr[4][64];
        if (quad == 0) {
#pragma unroll
            for (int j = 0; j < 4; j++) {
                sArr[wave][j * 16 + l15] = s[j];
                qArr[wave][j * 16 + l15] = q[j];
            }
        }
        __syncthreads();
        if (tid < 128) {
            int half = tid >> 6;
            int cc = tid & 63;
            float ss = sArr[half * 2][cc] + sArr[half * 2 + 1][cc];
            float qq = qArr[half * 2][cc] + qArr[half * 2 + 1][cc];
            int colI = n0 + half * 64 + cc;
            psum[(size_t)blockIdx.y * N + colI] = ss;
            psumsq[(size_t)blockIdx.y * N + colI] = qq;
        }
    }
}

// ---------------- bf16 gather, C=256 channels (no stats) --------------------

template <bool OUT_BF16>
__global__ __launch_bounds__(256) void gather_bf_kernel(
    const ushort* __restrict__ xl, const int* __restrict__ rowptr,
    const int* __restrict__ adj, const float* __restrict__ dis,
    void* __restrict__ h) {
    int v = blockIdx.x;
    int wave = threadIdx.x >> 6;
    int lane = threadIdx.x & 63;
    float dv = dis[v];

    float acc[4] = {0.f, 0.f, 0.f, 0.f};
    int e0 = rowptr[v], e1 = rowptr[v + 1];
    for (int e = e0 + wave; e < e1; e += 4) {
        int r = adj[e];
        float wgt = dis[r] * dv;
        ushort4 u = ((const ushort4*)xl)[(size_t)r * 64 + lane];
        acc[0] = fmaf(bf2f(u.x), wgt, acc[0]);
        acc[1] = fmaf(bf2f(u.y), wgt, acc[1]);
        acc[2] = fmaf(bf2f(u.z), wgt, acc[2]);
        acc[3] = fmaf(bf2f(u.w), wgt, acc[3]);
    }

    __shared__ float4 red[4][64];
    red[wave][lane] = make_float4(acc[0], acc[1], acc[2], acc[3]);
    __syncthreads();
    if (wave == 0) {
        float4 s = red[0][lane];
        float4 b = red[1][lane];
        float4 c = red[2][lane];
        float4 d = red[3][lane];
        s.x += b.x + c.x + d.x;
        s.y += b.y + c.y + d.y;
        s.z += b.z + c.z + d.z;
        s.w += b.w + c.w + d.w;
        ushort4 u = ((const ushort4*)xl)[(size_t)v * 64 + lane];
        float w2 = dv * dv;
        s.x = fmaf(bf2f(u.x), w2, s.x);
        s.y = fmaf(bf2f(u.y), w2, s.y);
        s.z = fmaf(bf2f(u.z), w2, s.z);
        s.w = fmaf(bf2f(u.w), w2, s.w);
        if (OUT_BF16) {
            ushort4 o;
            o.x = f2bf(s.x); o.y = f2bf(s.y); o.z = f2bf(s.z); o.w = f2bf(s.w);
            ((ushort4*)h)[(size_t)v * 64 + lane] = o;
        } else {
            ((float4*)h)[(size_t)v * 64 + lane] = s;
        }
    }
}

// ---------------- BN2 partial stats, layout [chunk][C] ----------------------

__global__ __launch_bounds__(256) void bn_partial_kernel(
    const float* __restrict__ h, float* __restrict__ psum, float* __restrict__ psumsq,
    int N, int IC, int rows_per_chunk) {
    int groups = IC >> 2;          // 64 for C=256
    int rpi = 256 / groups;        // 4
    int t = threadIdx.x;
    int g = t & (groups - 1);
    int ro = t / groups;
    int r0 = blockIdx.x * rows_per_chunk;
    int r1 = min(r0 + rows_per_chunk, N);

    float4 s = make_float4(0.f, 0.f, 0.f, 0.f);
    float4 q = make_float4(0.f, 0.f, 0.f, 0.f);
    for (int r = r0 + ro; r < r1; r += rpi) {
        float4 v = *(const float4*)(h + (size_t)r * IC + g * 4);
        s.x += v.x; s.y += v.y; s.z += v.z; s.w += v.w;
        q.x += v.x * v.x; q.y += v.y * v.y; q.z += v.z * v.z; q.w += v.w * v.w;
    }

    __shared__ float4 redS[256];
    __shared__ float4 redQ[256];
    redS[t] = s;
    redQ[t] = q;
    __syncthreads();
    if (ro == 0) {
        for (int i = 1; i < rpi; i++) {
            float4 o = redS[t + i * groups];
            s.x += o.x; s.y += o.y; s.z += o.z; s.w += o.w;
            float4 p = redQ[t + i * groups];
            q.x += p.x; q.y += p.y; q.z += p.z; q.w += p.w;
        }
        ((float4*)(psum + (size_t)blockIdx.x * IC))[g] = s;
        ((float4*)(psumsq + (size_t)blockIdx.x * IC))[g] = q;
    }
}

// ---------------- fused: redundant reduce1 -> BN1+ReLU+cast stream ----------
// psum layout [chunks][IC]; lane-per-channel coalesced, 4-way ILP accumulators.

__global__ __launch_bounds__(256) void bn_apply_fused_kernel(
    const ushort* __restrict__ h, const float* __restrict__ psum,
    const float* __restrict__ psumsq, const float* __restrict__ gamma,
    const float* __restrict__ beta, ushort* __restrict__ out,
    int N, int IC, int chunks, int n8) {
    __shared__ float sc[512];
    __shared__ float sh[512];
    int t = threadIdx.x;
    float invN = 1.0f / (float)N;
    for (int c = t; c < IC; c += 256) {
        float s0 = 0.f, s1 = 0.f, s2 = 0.f, s3 = 0.f;
        float q0 = 0.f, q1 = 0.f, q2 = 0.f, q3 = 0.f;
        int k = 0;
        for (; k + 3 < chunks; k += 4) {
            s0 += psum[(size_t)(k + 0) * IC + c];
            s1 += psum[(size_t)(k + 1) * IC + c];
            s2 += psum[(size_t)(k + 2) * IC + c];
            s3 += psum[(size_t)(k + 3) * IC + c];
            q0 += psumsq[(size_t)(k + 0) * IC + c];
            q1 += psumsq[(size_t)(k + 1) * IC + c];
            q2 += psumsq[(size_t)(k + 2) * IC + c];
            q3 += psumsq[(size_t)(k + 3) * IC + c];
        }
        for (; k < chunks; k++) {
            s0 += psum[(size_t)k * IC + c];
            q0 += psumsq[(size_t)k * IC + c];
        }
        float s = (s0 + s1) + (s2 + s3);
        float q = (q0 + q1) + (q2 + q3);
        float mean = s * invN;
        float var = q * invN - mean * mean;
        float scv = gamma[c] * rsqrtf(var + BN_EPS);
        sc[c] = scv;
        sh[c] = beta[c] - mean * scv;
    }
    __syncthreads();

    int IC8 = IC >> 3;
    for (int i = blockIdx.x * 256 + t; i < n8; i += gridDim.x * 256) {
        int c8 = (i & (IC8 - 1)) * 8;
        ushort4 a = ((const ushort4*)h)[2 * i];
        ushort4 b = ((const ushort4*)h)[2 * i + 1];
        ushort4 oa, ob;
        oa.x = f2bf(fmaxf(fmaf(bf2f(a.x), sc[c8 + 0], sh[c8 + 0]), 0.f));
        oa.y = f2bf(fmaxf(fmaf(bf2f(a.y), sc[c8 + 1], sh[c8 + 1]), 0.f));
        oa.z = f2bf(fmaxf(fmaf(bf2f(a.z), sc[c8 + 2], sh[c8 + 2]), 0.f));
        oa.w = f2bf(fmaxf(fmaf(bf2f(a.w), sc[c8 + 3], sh[c8 + 3]), 0.f));
        ob.x = f2bf(fmaxf(fmaf(bf2f(b.x), sc[c8 + 4], sh[c8 + 4]), 0.f));
        ob.y = f2bf(fmaxf(fmaf(bf2f(b.y), sc[c8 + 5], sh[c8 + 5]), 0.f));
        ob.z = f2bf(fmaxf(fmaf(bf2f(b.z), sc[c8 + 6], sh[c8 + 6]), 0.f));
        ob.w = f2bf(fmaxf(fmaf(bf2f(b.w), sc[c8 + 7], sh[c8 + 7]), 0.f));
        ((ushort4*)out)[2 * i] = oa;
        ((ushort4*)out)[2 * i + 1] = ob;
    }
}

// ---------------- fused: redundant reduce2 -> relu(bn2(h2)+x) stream --------
// psum layout [chunks][C]; lane-per-channel coalesced reduce; large grid.

__global__ __launch_bounds__(256) void final_fused_kernel(
    const float* __restrict__ h2, const float* __restrict__ x,
    const float* __restrict__ psum, const float* __restrict__ psumsq,
    const float* __restrict__ gamma, const float* __restrict__ beta,
    float* __restrict__ out, int N, int C, int chunks, int total4) {
    __shared__ float sc[256];
    __shared__ float sh[256];
    int t = threadIdx.x;
    float invN = 1.0f / (float)N;
    {
        int c = t;  // C == 256 == blockDim
        float s0 = 0.f, s1 = 0.f, s2 = 0.f, s3 = 0.f;
        float q0 = 0.f, q1 = 0.f, q2 = 0.f, q3 = 0.f;
        for (int k = 0; k < chunks; k += 4) {
            s0 += psum[(size_t)(k + 0) * C + c];
            s1 += psum[(size_t)(k + 1) * C + c];
            s2 += psum[(size_t)(k + 2) * C + c];
            s3 += psum[(size_t)(k + 3) * C + c];
            q0 += psumsq[(size_t)(k + 0) * C + c];
            q1 += psumsq[(size_t)(k + 1) * C + c];
            q2 += psumsq[(size_t)(k + 2) * C + c];
            q3 += psumsq[(size_t)(k + 3) * C + c];
        }
        float s = (s0 + s1) + (s2 + s3);
        float q = (q0 + q1) + (q2 + q3);
        float mean = s * invN;
        float var = q * invN - mean * mean;
        float scv = gamma[c] * rsqrtf(var + BN_EPS);
        sc[c] = scv;
        sh[c] = beta[c] - mean * scv;
    }
    __syncthreads();

    int C4 = C >> 2;
    for (int i = blockIdx.x * 256 + t; i < total4; i += gridDim.x * 256) {
        int c4 = (i & (C4 - 1)) * 4;
        float4 h = ((const float4*)h2)[i];
        float4 xv = ((const float4*)x)[i];
        float4 o;
        o.x = fmaxf(fmaf(h.x, sc[c4 + 0], sh[c4 + 0]) + xv.x, 0.f);
        o.y = fmaxf(fmaf(h.y, sc[c4 + 1], sh[c4 + 1]) + xv.y, 0.f);
        o.z = fmaxf(fmaf(h.z, sc[c4 + 2], sh[c4 + 2]) + xv.z, 0.f);
        o.w = fmaxf(fmaf(h.w, sc[c4 + 3], sh[c4 + 3]) + xv.w, 0.f);
        ((float4*)out)[i] = o;
    }
}

// ---------------- launch ----------------

extern "C" void kernel_launch(void* const* d_in, const int* in_sizes, int n_in,
                              void* d_out, int out_size, void* d_ws, size_t ws_size,
                              hipStream_t stream) {
    const float* x  = (const float*)d_in[0];
    const int*   es = (const int*)d_in[1];
    const float* W1 = (const float*)d_in[2];
    const float* g1 = (const float*)d_in[3];
    const float* b1 = (const float*)d_in[4];
    const float* W2 = (const float*)d_in[5];
    const float* g2 = (const float*)d_in[6];
    const float* b2 = (const float*)d_in[7];
    float* out = (float*)d_out;

    const int E  = in_sizes[1] / 2;
    const int IC = in_sizes[3];   // 512
    const int C  = in_sizes[7];   // 256
    const int N  = in_sizes[0] / C;
    const int MTILES = (N + 127) / 128;   // 79
    const int CHUNKS2 = 128;

    const int* row = es;
    const int* col = es + E;

    // ---- workspace layout (cnt first: single memset) ----
    char* w = (char*)d_ws;
    size_t off = 0;
    auto alloc = [&](size_t bytes) -> void* {
        void* p = w + off;
        off = (off + bytes + 255) & ~(size_t)255;
        return p;
    };
    int*   cnt     = (int*)alloc((size_t)N * 4);
    float* dis     = (float*)alloc((size_t)N * 4);
    int*   rowptr  = (int*)alloc((size_t)(N + 1) * 4);
    int*   cursor  = (int*)alloc((size_t)N * 4);
    int*   adj     = (int*)alloc((size_t)E * 4);
    float* psum1   = (float*)alloc((size_t)MTILES * IC * 4);
    float* psumsq1 = (float*)alloc((size_t)MTILES * IC * 4);
    float* psum2   = (float*)alloc((size_t)CHUNKS2 * C * 4);
    float* psumsq2 = (float*)alloc((size_t)CHUNKS2 * C * 4);
    ushort* xbf    = (ushort*)alloc((size_t)N * C * 2);
    ushort* W1bf   = (ushort*)alloc((size_t)IC * C * 2);
    ushort* W2bf   = (ushort*)alloc((size_t)IC * C * 2);
    ushort* g1x    = (ushort*)alloc((size_t)N * C * 2);
    ushort* h1raw  = (ushort*)alloc((size_t)N * IC * 2);  // GEMM1 out, bf16
    ushort* h1bf   = (ushort*)alloc((size_t)N * IC * 2);  // BN1+ReLU out
    ushort* xl2bf  = (ushort*)alloc((size_t)N * C * 2);
    float*  h2     = (float*)alloc((size_t)N * C * 4);

    hipMemsetAsync(cnt, 0, (size_t)N * 4, stream);

    // ---- prep: degree count + bf16 casts ----
    {
        int n4x = N * C / 4, n4w = IC * C / 4;
        int tot = E + n4x + 2 * n4w;
        prep_kernel<<<(tot + 255) / 256, 256, 0, stream>>>(
            col, cnt, x, W1, W2, xbf, W1bf, W2bf, E, n4x, n4w);
    }
    scan_dis_kernel<<<1, 1024, 0, stream>>>(cnt, dis, rowptr, cursor, N);
    scatter_kernel<<<(E + 255) / 256, 256, 0, stream>>>(row, col, cursor, adj, E);

    // ---- layer 1: g1x = A_norm(x); h1raw = g1x @ W1^T (bf16 + stats1) ----
    gather_bf_kernel<true><<<N, 256, 0, stream>>>(xbf, rowptr, adj, dis, g1x);
    {
        dim3 grid(IC / 128, MTILES);
        gemm_mfma_kernel<true, true><<<grid, 256, 0, stream>>>(
            g1x, W1bf, h1raw, psum1, psumsq1, N, IC, C);
    }
    // fused reduce1 + BN1 + ReLU + cast
    bn_apply_fused_kernel<<<640, 256, 0, stream>>>(
        h1raw, psum1, psumsq1, g1, b1, h1bf, N, IC, MTILES, N * IC / 8);

    // ---- layer 2: xl2 = h1bf @ W2^T (bf16); h2 = A_norm(xl2) ----
    {
        dim3 grid(C / 128, MTILES);
        gemm_mfma_kernel<true, false><<<grid, 256, 0, stream>>>(
            h1bf, W2bf, xl2bf, nullptr, nullptr, N, C, IC);
    }
    gather_bf_kernel<false><<<N, 256, 0, stream>>>(xl2bf, rowptr, adj, dis, h2);
    {
        int rpc = (N + CHUNKS2 - 1) / CHUNKS2;
        bn_partial_kernel<<<CHUNKS2, 256, 0, stream>>>(h2, psum2, psumsq2, N, C, rpc);
    }

    // ---- fused reduce2 + relu(bn2(h2) + x) ----
    final_fused_kernel<<<1250, 256, 0, stream>>>(
        h2, x, psum2, psumsq2, g2, b2, out, N, C, CHUNKS2, N * C / 4);
}

// Round 16
// 222.911 us; speedup vs baseline: 1.2566x; 1.0588x over previous
//
#include <hip/hip_runtime.h>

#define BN_EPS 1e-5f

typedef __attribute__((ext_vector_type(8))) short short8;
typedef __attribute__((ext_vector_type(4))) float floatx4;

#define GLL(gp, lp)                                                            \
    __builtin_amdgcn_global_load_lds(                                          \
        (const __attribute__((address_space(1))) void*)(gp),                   \
        (__attribute__((address_space(3))) void*)(lp), 16, 0, 0)

__device__ inline unsigned short f2bf(float f) {
    unsigned int u = __float_as_uint(f);
    unsigned int r = (u + 0x7FFF + ((u >> 16) & 1)) >> 16;  // RNE
    return (unsigned short)r;
}

__device__ inline float bf2f(unsigned short u) {
    return __uint_as_float(((unsigned int)u) << 16);
}

// ---------------- prep: count in-degree + fp32->bf16 casts (merged) --------

__global__ void prep_kernel(const int* __restrict__ col, int* __restrict__ cnt,
                            const float* __restrict__ x, const float* __restrict__ W1,
                            const float* __restrict__ W2, ushort* __restrict__ xbf,
                            ushort* __restrict__ W1bf, ushort* __restrict__ W2bf,
                            int E, int n4x, int n4w) {
    int i = blockIdx.x * blockDim.x + threadIdx.x;
    if (i < E) {
        atomicAdd(&cnt[col[i]], 1);
        return;
    }
    int j = i - E;
    const float* src;
    ushort* dst;
    if (j < n4x) { src = x; dst = xbf; }
    else if (j < n4x + n4w) { src = W1; dst = W1bf; j -= n4x; }
    else if (j < n4x + 2 * n4w) { src = W2; dst = W2bf; j -= n4x + n4w; }
    else return;
    float4 v = ((const float4*)src)[j];
    ushort4 o;
    o.x = f2bf(v.x); o.y = f2bf(v.y); o.z = f2bf(v.z); o.w = f2bf(v.w);
    ((ushort4*)dst)[j] = o;
}

// single-block scan over N counts -> rowptr/cursor; also computes dis.
__global__ __launch_bounds__(1024) void scan_dis_kernel(
    const int* __restrict__ cnt, float* __restrict__ dis,
    int* __restrict__ rowptr, int* __restrict__ cursor, int N) {
    __shared__ int sums[1024];
    int t = threadIdx.x;
    int per = (N + 1023) / 1024;
    int start = t * per;
    int local = 0;
    for (int i = 0; i < per; i++) {
        int idx = start + i;
        if (idx < N) {
            int cv = cnt[idx];
            local += cv;
            dis[idx] = rsqrtf((float)(cv + 1));   // +1 self loop
        }
    }
    sums[t] = local;
    __syncthreads();
    for (int off = 1; off < 1024; off <<= 1) {
        int v = (t >= off) ? sums[t - off] : 0;
        __syncthreads();
        sums[t] += v;
        __syncthreads();
    }
    int run = (t == 0) ? 0 : sums[t - 1];
    for (int i = 0; i < per; i++) {
        int idx = start + i;
        if (idx < N) {
            rowptr[idx] = run;
            cursor[idx] = run;
            run += cnt[idx];
        }
    }
    if (t == 0) rowptr[N] = sums[1023];
}

__global__ void scatter_kernel(const int* __restrict__ row, const int* __restrict__ col,
                               int* __restrict__ cursor, int* __restrict__ adj, int E) {
    int e = blockIdx.x * blockDim.x + threadIdx.x;
    if (e < E) {
        int pos = atomicAdd(&cursor[col[e]], 1);
        adj[pos] = row[e];
    }
}

// ---------------- MFMA GEMM: C[M,N] = A[M,K] @ B[N,K]^T (bf16 in) ----------
// STATS: epilogue emits per-column partial sum/sumsq (fp32 acc) into
// psum[blockIdx.y * N + col]  ([chunk][col]: coalesced stores).

template <bool OUT_BF16, bool STATS>
__global__ __launch_bounds__(256) void gemm_mfma_kernel(
    const ushort* __restrict__ A, const ushort* __restrict__ B,
    void* __restrict__ Cout, float* __restrict__ psum, float* __restrict__ psumsq,
    int M, int N, int K) {
    __shared__ ushort As[128 * 32];
    __shared__ ushort Bs[128 * 32];
    int tid = threadIdx.x;
    int wave = tid >> 6;
    int lane = tid & 63;
    int quad = lane >> 4;
    int l15 = lane & 15;
    int m0 = blockIdx.y * 128;
    int n0 = blockIdx.x * 128;

    int srow = lane >> 2;
    int skoff = (lane & 3) * 8;

    floatx4 acc[4][4];
#pragma unroll
    for (int i = 0; i < 4; i++)
#pragma unroll
        for (int j = 0; j < 4; j++) acc[i][j] = (floatx4){0.f, 0.f, 0.f, 0.f};

    int wm = (wave & 1) * 64;
    int wn = (wave >> 1) * 64;

    for (int k0 = 0; k0 < K; k0 += 32) {
#pragma unroll
        for (int cc = 0; cc < 2; cc++) {
            int c = wave * 2 + cc;
            int arow = m0 + c * 16 + srow;
            arow = min(arow, M - 1);
            const ushort* ga = A + (size_t)arow * K + k0 + skoff;
            GLL(ga, (char*)As + c * 1024);
            int brow = n0 + c * 16 + srow;
            const ushort* gb = B + (size_t)brow * K + k0 + skoff;
            GLL(gb, (char*)Bs + c * 1024);
        }
        __syncthreads();

        short8 af[4], bfr[4];
#pragma unroll
        for (int i = 0; i < 4; i++) {
            int r = wm + i * 16 + l15;
            af[i] = *(const short8*)(As + r * 32 + quad * 8);
        }
#pragma unroll
        for (int j = 0; j < 4; j++) {
            int r = wn + j * 16 + l15;
            bfr[j] = *(const short8*)(Bs + r * 32 + quad * 8);
        }
#pragma unroll
        for (int i = 0; i < 4; i++)
#pragma unroll
            for (int j = 0; j < 4; j++)
                acc[i][j] = __builtin_amdgcn_mfma_f32_16x16x32_bf16(af[i], bfr[j], acc[i][j], 0, 0, 0);
        __syncthreads();
    }

#pragma unroll
    for (int i = 0; i < 4; i++) {
#pragma unroll
        for (int r = 0; r < 4; r++) {
            int row = m0 + wm + i * 16 + quad * 4 + r;
            if (row < M) {
                if (OUT_BF16) {
                    ushort* cp = (ushort*)Cout + (size_t)row * N + n0 + wn + l15;
#pragma unroll
                    for (int j = 0; j < 4; j++) cp[j * 16] = f2bf(acc[i][j][r]);
                } else {
                    float* cp = (float*)Cout + (size_t)row * N + n0 + wn + l15;
#pragma unroll
                    for (int j = 0; j < 4; j++) cp[j * 16] = acc[i][j][r];
                }
            }
        }
    }

    if (STATS) {
        float s[4] = {0.f, 0.f, 0.f, 0.f};
        float q[4] = {0.f, 0.f, 0.f, 0.f};
#pragma unroll
        for (int i = 0; i < 4; i++) {
#pragma unroll
            for (int r = 0; r < 4; r++) {
                if (m0 + wm + i * 16 + quad * 4 + r < M) {
#pragma unroll
                    for (int j = 0; j < 4; j++) {
                        float v = acc[i][j][r];
                        s[j] += v;
                        q[j] += v * v;
                    }
                }
            }
        }
#pragma unroll
        for (int j = 0; j < 4; j++) {
            s[j] += __shfl_xor(s[j], 16, 64);
            s[j] += __shfl_xor(s[j], 32, 64);
            q[j] += __shfl_xor(q[j], 16, 64);
            q[j] += __shfl_xor(q[j], 32, 64);
        }
        __shared__ float sArr[4][64];
        __shared__ float qArr[4][64];
        if (quad == 0) {
#pragma unroll
            for (int j = 0; j < 4; j++) {
                sArr[wave][j * 16 + l15] = s[j];
                qArr[wave][j * 16 + l15] = q[j];
            }
        }
        __syncthreads();
        if (tid < 128) {
            int half = tid >> 6;
            int cc = tid & 63;
            float ss = sArr[half * 2][cc] + sArr[half * 2 + 1][cc];
            float qq = qArr[half * 2][cc] + qArr[half * 2 + 1][cc];
            int colI = n0 + half * 64 + cc;
            psum[(size_t)blockIdx.y * N + colI] = ss;
            psumsq[(size_t)blockIdx.y * N + colI] = qq;
        }
    }
}

// ---------------- bf16 gather, C=256 channels ----------------

template <bool OUT_BF16>
__global__ __launch_bounds__(256) void gather_bf_kernel(
    const ushort* __restrict__ xl, const int* __restrict__ rowptr,
    const int* __restrict__ adj, const float* __restrict__ dis,
    void* __restrict__ h) {
    int v = blockIdx.x;
    int wave = threadIdx.x >> 6;
    int lane = threadIdx.x & 63;
    float dv = dis[v];

    float acc[4] = {0.f, 0.f, 0.f, 0.f};
    int e0 = rowptr[v], e1 = rowptr[v + 1];
    for (int e = e0 + wave; e < e1; e += 4) {
        int r = adj[e];
        float wgt = dis[r] * dv;
        ushort4 u = ((const ushort4*)xl)[(size_t)r * 64 + lane];
        acc[0] = fmaf(bf2f(u.x), wgt, acc[0]);
        acc[1] = fmaf(bf2f(u.y), wgt, acc[1]);
        acc[2] = fmaf(bf2f(u.z), wgt, acc[2]);
        acc[3] = fmaf(bf2f(u.w), wgt, acc[3]);
    }

    __shared__ float4 red[4][64];
    red[wave][lane] = make_float4(acc[0], acc[1], acc[2], acc[3]);
    __syncthreads();
    if (wave == 0) {
        float4 s = red[0][lane];
        float4 b = red[1][lane];
        float4 c = red[2][lane];
        float4 d = red[3][lane];
        s.x += b.x + c.x + d.x;
        s.y += b.y + c.y + d.y;
        s.z += b.z + c.z + d.z;
        s.w += b.w + c.w + d.w;
        ushort4 u = ((const ushort4*)xl)[(size_t)v * 64 + lane];
        float w2 = dv * dv;
        s.x = fmaf(bf2f(u.x), w2, s.x);
        s.y = fmaf(bf2f(u.y), w2, s.y);
        s.z = fmaf(bf2f(u.z), w2, s.z);
        s.w = fmaf(bf2f(u.w), w2, s.w);
        if (OUT_BF16) {
            ushort4 o;
            o.x = f2bf(s.x); o.y = f2bf(s.y); o.z = f2bf(s.z); o.w = f2bf(s.w);
            ((ushort4*)h)[(size_t)v * 64 + lane] = o;
        } else {
            ((float4*)h)[(size_t)v * 64 + lane] = s;
        }
    }
}

// ---------------- BN1 reduce: thread-per-channel over [chunk][IC] -----------
// lane c reads psum[k*IC+c] (coalesced across lanes); 4-way ILP over k.

__global__ __launch_bounds__(256) void bn_reduce_tpc_kernel(
    const float* __restrict__ psum, const float* __restrict__ psumsq,
    const float* __restrict__ gamma, const float* __restrict__ beta,
    float* __restrict__ scale, float* __restrict__ shift,
    int N, int IC, int chunks) {
    int c = blockIdx.x * 256 + threadIdx.x;
    if (c >= IC) return;
    float s0 = 0.f, s1 = 0.f, s2 = 0.f, s3 = 0.f;
    float q0 = 0.f, q1 = 0.f, q2 = 0.f, q3 = 0.f;
    int k = 0;
    for (; k + 3 < chunks; k += 4) {
        s0 += psum[(size_t)(k + 0) * IC + c];
        s1 += psum[(size_t)(k + 1) * IC + c];
        s2 += psum[(size_t)(k + 2) * IC + c];
        s3 += psum[(size_t)(k + 3) * IC + c];
        q0 += psumsq[(size_t)(k + 0) * IC + c];
        q1 += psumsq[(size_t)(k + 1) * IC + c];
        q2 += psumsq[(size_t)(k + 2) * IC + c];
        q3 += psumsq[(size_t)(k + 3) * IC + c];
    }
    for (; k < chunks; k++) {
        s0 += psum[(size_t)k * IC + c];
        q0 += psumsq[(size_t)k * IC + c];
    }
    float s = (s0 + s1) + (s2 + s3);
    float q = (q0 + q1) + (q2 + q3);
    float invN = 1.0f / (float)N;
    float mean = s * invN;
    float var = q * invN - mean * mean;
    float sc = gamma[c] * rsqrtf(var + BN_EPS);
    scale[c] = sc;
    shift[c] = beta[c] - mean * sc;
}

// ---------------- BN2 partial stats (channel-major [C][chunks]) -------------

__global__ __launch_bounds__(256) void bn_partial_kernel(
    const float* __restrict__ h, float* __restrict__ psum, float* __restrict__ psumsq,
    int N, int IC, int rows_per_chunk, int chunks) {
    int groups = IC >> 2;
    int rpi = 256 / groups;
    int t = threadIdx.x;
    int g = t & (groups - 1);
    int ro = t / groups;
    int r0 = blockIdx.x * rows_per_chunk;
    int r1 = min(r0 + rows_per_chunk, N);

    float4 s = make_float4(0.f, 0.f, 0.f, 0.f);
    float4 q = make_float4(0.f, 0.f, 0.f, 0.f);
    for (int r = r0 + ro; r < r1; r += rpi) {
        float4 v = *(const float4*)(h + (size_t)r * IC + g * 4);
        s.x += v.x; s.y += v.y; s.z += v.z; s.w += v.w;
        q.x += v.x * v.x; q.y += v.y * v.y; q.z += v.z * v.z; q.w += v.w * v.w;
    }

    __shared__ float4 redS[256];
    __shared__ float4 redQ[256];
    redS[t] = s;
    redQ[t] = q;
    __syncthreads();
    if (ro == 0) {
        for (int i = 1; i < rpi; i++) {
            float4 o = redS[t + i * groups];
            s.x += o.x; s.y += o.y; s.z += o.z; s.w += o.w;
            float4 p = redQ[t + i * groups];
            q.x += p.x; q.y += p.y; q.z += p.z; q.w += p.w;
        }
        int k = blockIdx.x;
        psum[(size_t)(4 * g + 0) * chunks + k] = s.x;
        psum[(size_t)(4 * g + 1) * chunks + k] = s.y;
        psum[(size_t)(4 * g + 2) * chunks + k] = s.z;
        psum[(size_t)(4 * g + 3) * chunks + k] = s.w;
        psumsq[(size_t)(4 * g + 0) * chunks + k] = q.x;
        psumsq[(size_t)(4 * g + 1) * chunks + k] = q.y;
        psumsq[(size_t)(4 * g + 2) * chunks + k] = q.z;
        psumsq[(size_t)(4 * g + 3) * chunks + k] = q.w;
    }
}

// one wave per channel; coalesced lane-parallel reduce -> scale/shift.
__global__ __launch_bounds__(256) void bn_reduce_kernel(
    const float* __restrict__ psum, const float* __restrict__ psumsq,
    const float* __restrict__ gamma, const float* __restrict__ beta,
    float* __restrict__ scale, float* __restrict__ shift,
    int N, int chunks) {
    int wave = threadIdx.x >> 6;
    int lane = threadIdx.x & 63;
    int c = blockIdx.x * 4 + wave;
    float s = 0.f, q = 0.f;
    for (int k = lane; k < chunks; k += 64) {
        s += psum[(size_t)c * chunks + k];
        q += psumsq[(size_t)c * chunks + k];
    }
#pragma unroll
    for (int off = 32; off > 0; off >>= 1) {
        s += __shfl_down(s, off, 64);
        q += __shfl_down(q, off, 64);
    }
    if (lane == 0) {
        float invN = 1.0f / (float)N;
        float mean = s * invN;
        float var = q * invN - mean * mean;
        float sc = gamma[c] * rsqrtf(var + BN_EPS);
        scale[c] = sc;
        shift[c] = beta[c] - mean * sc;
    }
}

// BN+ReLU applied to bf16 h1, bf16 out (feeds GEMM2's A); 8 elems/thread.
__global__ void bn_apply_bb_kernel(const ushort* __restrict__ h,
                                   const float* __restrict__ scale,
                                   const float* __restrict__ shift,
                                   ushort* __restrict__ out, int n8, int IC8) {
    int i = blockIdx.x * blockDim.x + threadIdx.x;
    if (i >= n8) return;
    int c8 = (i & (IC8 - 1)) * 8;
    ushort4 a = ((const ushort4*)h)[2 * i];
    ushort4 b = ((const ushort4*)h)[2 * i + 1];
    ushort4 oa, ob;
    oa.x = f2bf(fmaxf(fmaf(bf2f(a.x), scale[c8 + 0], shift[c8 + 0]), 0.f));
    oa.y = f2bf(fmaxf(fmaf(bf2f(a.y), scale[c8 + 1], shift[c8 + 1]), 0.f));
    oa.z = f2bf(fmaxf(fmaf(bf2f(a.z), scale[c8 + 2], shift[c8 + 2]), 0.f));
    oa.w = f2bf(fmaxf(fmaf(bf2f(a.w), scale[c8 + 3], shift[c8 + 3]), 0.f));
    ob.x = f2bf(fmaxf(fmaf(bf2f(b.x), scale[c8 + 4], shift[c8 + 4]), 0.f));
    ob.y = f2bf(fmaxf(fmaf(bf2f(b.y), scale[c8 + 5], shift[c8 + 5]), 0.f));
    ob.z = f2bf(fmaxf(fmaf(bf2f(b.z), scale[c8 + 6], shift[c8 + 6]), 0.f));
    ob.w = f2bf(fmaxf(fmaf(bf2f(b.w), scale[c8 + 7], shift[c8 + 7]), 0.f));
    ((ushort4*)out)[2 * i] = oa;
    ((ushort4*)out)[2 * i + 1] = ob;
}

// ---------------- final: out = relu(bn2(h2) + x), large grid ----------------

__global__ void final_kernel(const float* __restrict__ h2, const float* __restrict__ x,
                             const float* __restrict__ scale, const float* __restrict__ shift,
                             float* __restrict__ out, int total4, int C4) {
    int idx = blockIdx.x * blockDim.x + threadIdx.x;
    if (idx >= total4) return;
    int c4 = (idx % C4) * 4;
    float4 h = ((const float4*)h2)[idx];
    float4 xv = ((const float4*)x)[idx];
    float4 o;
    o.x = fmaxf(fmaf(h.x, scale[c4 + 0], shift[c4 + 0]) + xv.x, 0.f);
    o.y = fmaxf(fmaf(h.y, scale[c4 + 1], shift[c4 + 1]) + xv.y, 0.f);
    o.z = fmaxf(fmaf(h.z, scale[c4 + 2], shift[c4 + 2]) + xv.z, 0.f);
    o.w = fmaxf(fmaf(h.w, scale[c4 + 3], shift[c4 + 3]) + xv.w, 0.f);
    ((float4*)out)[idx] = o;
}

// ---------------- launch ----------------

extern "C" void kernel_launch(void* const* d_in, const int* in_sizes, int n_in,
                              void* d_out, int out_size, void* d_ws, size_t ws_size,
                              hipStream_t stream) {
    const float* x  = (const float*)d_in[0];
    const int*   es = (const int*)d_in[1];
    const float* W1 = (const float*)d_in[2];
    const float* g1 = (const float*)d_in[3];
    const float* b1 = (const float*)d_in[4];
    const float* W2 = (const float*)d_in[5];
    const float* g2 = (const float*)d_in[6];
    const float* b2 = (const float*)d_in[7];
    float* out = (float*)d_out;

    const int E  = in_sizes[1] / 2;
    const int IC = in_sizes[3];   // 512
    const int C  = in_sizes[7];   // 256
    const int N  = in_sizes[0] / C;
    const int MTILES = (N + 127) / 128;   // 79
    const int CHUNKS2 = 512;

    const int* row = es;
    const int* col = es + E;

    // ---- workspace layout (cnt first: single memset) ----
    char* w = (char*)d_ws;
    size_t off = 0;
    auto alloc = [&](size_t bytes) -> void* {
        void* p = w + off;
        off = (off + bytes + 255) & ~(size_t)255;
        return p;
    };
    int*   cnt     = (int*)alloc((size_t)N * 4);
    float* dis     = (float*)alloc((size_t)N * 4);
    int*   rowptr  = (int*)alloc((size_t)(N + 1) * 4);
    int*   cursor  = (int*)alloc((size_t)N * 4);
    int*   adj     = (int*)alloc((size_t)E * 4);
    float* psum1   = (float*)alloc((size_t)MTILES * IC * 4);
    float* psumsq1 = (float*)alloc((size_t)MTILES * IC * 4);
    float* psum2   = (float*)alloc((size_t)C * CHUNKS2 * 4);
    float* psumsq2 = (float*)alloc((size_t)C * CHUNKS2 * 4);
    float* scale1  = (float*)alloc((size_t)IC * 4);
    float* shift1  = (float*)alloc((size_t)IC * 4);
    float* scale2  = (float*)alloc((size_t)C * 4);
    float* shift2  = (float*)alloc((size_t)C * 4);
    ushort* xbf    = (ushort*)alloc((size_t)N * C * 2);
    ushort* W1bf   = (ushort*)alloc((size_t)IC * C * 2);
    ushort* W2bf   = (ushort*)alloc((size_t)IC * C * 2);
    ushort* g1x    = (ushort*)alloc((size_t)N * C * 2);
    ushort* h1raw  = (ushort*)alloc((size_t)N * IC * 2);  // GEMM1 out, bf16
    ushort* h1bf   = (ushort*)alloc((size_t)N * IC * 2);  // BN1+ReLU out
    ushort* xl2bf  = (ushort*)alloc((size_t)N * C * 2);
    float*  h2     = (float*)alloc((size_t)N * C * 4);

    hipMemsetAsync(cnt, 0, (size_t)N * 4, stream);

    // ---- prep: degree count + bf16 casts ----
    {
        int n4x = N * C / 4, n4w = IC * C / 4;
        int tot = E + n4x + 2 * n4w;
        prep_kernel<<<(tot + 255) / 256, 256, 0, stream>>>(
            col, cnt, x, W1, W2, xbf, W1bf, W2bf, E, n4x, n4w);
    }
    scan_dis_kernel<<<1, 1024, 0, stream>>>(cnt, dis, rowptr, cursor, N);
    scatter_kernel<<<(E + 255) / 256, 256, 0, stream>>>(row, col, cursor, adj, E);

    // ---- layer 1: g1x = A_norm(x); h1raw = g1x @ W1^T (bf16 + stats1) ----
    gather_bf_kernel<true><<<N, 256, 0, stream>>>(xbf, rowptr, adj, dis, g1x);
    {
        dim3 grid(IC / 128, MTILES);
        gemm_mfma_kernel<true, true><<<grid, 256, 0, stream>>>(
            g1x, W1bf, h1raw, psum1, psumsq1, N, IC, C);
    }
    bn_reduce_tpc_kernel<<<(IC + 255) / 256, 256, 0, stream>>>(
        psum1, psumsq1, g1, b1, scale1, shift1, N, IC, MTILES);
    bn_apply_bb_kernel<<<((N * IC / 8) + 255) / 256, 256, 0, stream>>>(
        h1raw, scale1, shift1, h1bf, N * IC / 8, IC / 8);

    // ---- layer 2: xl2 = h1bf @ W2^T (bf16 out); h2 = A_norm(xl2) ----
    {
        dim3 grid(C / 128, MTILES);
        gemm_mfma_kernel<true, false><<<grid, 256, 0, stream>>>(
            h1bf, W2bf, xl2bf, nullptr, nullptr, N, C, IC);
    }
    gather_bf_kernel<false><<<N, 256, 0, stream>>>(xl2bf, rowptr, adj, dis, h2);
    {
        int rpc = (N + CHUNKS2 - 1) / CHUNKS2;
        bn_partial_kernel<<<CHUNKS2, 256, 0, stream>>>(h2, psum2, psumsq2, N, C, rpc, CHUNKS2);
    }
    bn_reduce_kernel<<<C / 4, 256, 0, stream>>>(psum2, psumsq2, g2, b2, scale2, shift2, N, CHUNKS2);

    // ---- epilogue: relu(bn2(h2) + x), saturating grid ----
    {
        int total4 = (N * C) / 4;
        final_kernel<<<(total4 + 255) / 256, 256, 0, stream>>>(h2, x, scale2, shift2, out, total4, C / 4);
    }
}

// Round 17
// 214.573 us; speedup vs baseline: 1.3054x; 1.0389x over previous
//
#include <hip/hip_runtime.h>

#define BN_EPS 1e-5f

typedef __attribute__((ext_vector_type(8))) short short8;
typedef __attribute__((ext_vector_type(4))) float floatx4;

#define GLL(gp, lp)                                                            \
    __builtin_amdgcn_global_load_lds(                                          \
        (const __attribute__((address_space(1))) void*)(gp),                   \
        (__attribute__((address_space(3))) void*)(lp), 16, 0, 0)

__device__ inline unsigned short f2bf(float f) {
    unsigned int u = __float_as_uint(f);
    unsigned int r = (u + 0x7FFF + ((u >> 16) & 1)) >> 16;  // RNE
    return (unsigned short)r;
}

__device__ inline float bf2f(unsigned short u) {
    return __uint_as_float(((unsigned int)u) << 16);
}

// ---------------- prep: count in-degree + fp32->bf16 casts (merged) --------

__global__ void prep_kernel(const int* __restrict__ col, int* __restrict__ cnt,
                            const float* __restrict__ x, const float* __restrict__ W1,
                            const float* __restrict__ W2, ushort* __restrict__ xbf,
                            ushort* __restrict__ W1bf, ushort* __restrict__ W2bf,
                            int E, int n4x, int n4w) {
    int i = blockIdx.x * blockDim.x + threadIdx.x;
    if (i < E) {
        atomicAdd(&cnt[col[i]], 1);
        return;
    }
    int j = i - E;
    const float* src;
    ushort* dst;
    if (j < n4x) { src = x; dst = xbf; }
    else if (j < n4x + n4w) { src = W1; dst = W1bf; j -= n4x; }
    else if (j < n4x + 2 * n4w) { src = W2; dst = W2bf; j -= n4x + n4w; }
    else return;
    float4 v = ((const float4*)src)[j];
    ushort4 o;
    o.x = f2bf(v.x); o.y = f2bf(v.y); o.z = f2bf(v.z); o.w = f2bf(v.w);
    ((ushort4*)dst)[j] = o;
}

// single-block scan over N counts -> rowptr/cursor; also computes dis.
__global__ __launch_bounds__(1024) void scan_dis_kernel(
    const int* __restrict__ cnt, float* __restrict__ dis,
    int* __restrict__ rowptr, int* __restrict__ cursor, int N) {
    __shared__ int sums[1024];
    int t = threadIdx.x;
    int per = (N + 1023) / 1024;
    int start = t * per;
    int local = 0;
    for (int i = 0; i < per; i++) {
        int idx = start + i;
        if (idx < N) {
            int cv = cnt[idx];
            local += cv;
            dis[idx] = rsqrtf((float)(cv + 1));   // +1 self loop
        }
    }
    sums[t] = local;
    __syncthreads();
    for (int off = 1; off < 1024; off <<= 1) {
        int v = (t >= off) ? sums[t - off] : 0;
        __syncthreads();
        sums[t] += v;
        __syncthreads();
    }
    int run = (t == 0) ? 0 : sums[t - 1];
    for (int i = 0; i < per; i++) {
        int idx = start + i;
        if (idx < N) {
            rowptr[idx] = run;
            cursor[idx] = run;
            run += cnt[idx];
        }
    }
    if (t == 0) rowptr[N] = sums[1023];
}

__global__ void scatter_kernel(const int* __restrict__ row, const int* __restrict__ col,
                               int* __restrict__ cursor, int* __restrict__ adj, int E) {
    int e = blockIdx.x * blockDim.x + threadIdx.x;
    if (e < E) {
        int pos = atomicAdd(&cursor[col[e]], 1);
        adj[pos] = row[e];
    }
}

// ---------------- MFMA GEMM: C[M,N] = A[M,K] @ B[N,K]^T (bf16 in) ----------
// STATS: epilogue emits per-column partial sum/sumsq (fp32 acc) into
// psum[col * chunks + blockIdx.y]  ([col][chunk], as in R13).

template <bool OUT_BF16, bool STATS>
__global__ __launch_bounds__(256) void gemm_mfma_kernel(
    const ushort* __restrict__ A, const ushort* __restrict__ B,
    void* __restrict__ Cout, float* __restrict__ psum, float* __restrict__ psumsq,
    int chunks, int M, int N, int K) {
    __shared__ ushort As[128 * 32];
    __shared__ ushort Bs[128 * 32];
    int tid = threadIdx.x;
    int wave = tid >> 6;
    int lane = tid & 63;
    int quad = lane >> 4;
    int l15 = lane & 15;
    int m0 = blockIdx.y * 128;
    int n0 = blockIdx.x * 128;

    int srow = lane >> 2;
    int skoff = (lane & 3) * 8;

    floatx4 acc[4][4];
#pragma unroll
    for (int i = 0; i < 4; i++)
#pragma unroll
        for (int j = 0; j < 4; j++) acc[i][j] = (floatx4){0.f, 0.f, 0.f, 0.f};

    int wm = (wave & 1) * 64;
    int wn = (wave >> 1) * 64;

    for (int k0 = 0; k0 < K; k0 += 32) {
#pragma unroll
        for (int cc = 0; cc < 2; cc++) {
            int c = wave * 2 + cc;
            int arow = m0 + c * 16 + srow;
            arow = min(arow, M - 1);
            const ushort* ga = A + (size_t)arow * K + k0 + skoff;
            GLL(ga, (char*)As + c * 1024);
            int brow = n0 + c * 16 + srow;
            const ushort* gb = B + (size_t)brow * K + k0 + skoff;
            GLL(gb, (char*)Bs + c * 1024);
        }
        __syncthreads();

        short8 af[4], bfr[4];
#pragma unroll
        for (int i = 0; i < 4; i++) {
            int r = wm + i * 16 + l15;
            af[i] = *(const short8*)(As + r * 32 + quad * 8);
        }
#pragma unroll
        for (int j = 0; j < 4; j++) {
            int r = wn + j * 16 + l15;
            bfr[j] = *(const short8*)(Bs + r * 32 + quad * 8);
        }
#pragma unroll
        for (int i = 0; i < 4; i++)
#pragma unroll
            for (int j = 0; j < 4; j++)
                acc[i][j] = __builtin_amdgcn_mfma_f32_16x16x32_bf16(af[i], bfr[j], acc[i][j], 0, 0, 0);
        __syncthreads();
    }

#pragma unroll
    for (int i = 0; i < 4; i++) {
#pragma unroll
        for (int r = 0; r < 4; r++) {
            int row = m0 + wm + i * 16 + quad * 4 + r;
            if (row < M) {
                if (OUT_BF16) {
                    ushort* cp = (ushort*)Cout + (size_t)row * N + n0 + wn + l15;
#pragma unroll
                    for (int j = 0; j < 4; j++) cp[j * 16] = f2bf(acc[i][j][r]);
                } else {
                    float* cp = (float*)Cout + (size_t)row * N + n0 + wn + l15;
#pragma unroll
                    for (int j = 0; j < 4; j++) cp[j * 16] = acc[i][j][r];
                }
            }
        }
    }

    if (STATS) {
        float s[4] = {0.f, 0.f, 0.f, 0.f};
        float q[4] = {0.f, 0.f, 0.f, 0.f};
#pragma unroll
        for (int i = 0; i < 4; i++) {
#pragma unroll
            for (int r = 0; r < 4; r++) {
                if (m0 + wm + i * 16 + quad * 4 + r < M) {
#pragma unroll
                    for (int j = 0; j < 4; j++) {
                        float v = acc[i][j][r];
                        s[j] += v;
                        q[j] += v * v;
                    }
                }
            }
        }
#pragma unroll
        for (int j = 0; j < 4; j++) {
            s[j] += __shfl_xor(s[j], 16, 64);
            s[j] += __shfl_xor(s[j], 32, 64);
            q[j] += __shfl_xor(q[j], 16, 64);
            q[j] += __shfl_xor(q[j], 32, 64);
        }
        __shared__ float sArr[4][64];
        __shared__ float qArr[4][64];
        if (quad == 0) {
#pragma unroll
            for (int j = 0; j < 4; j++) {
                sArr[wave][j * 16 + l15] = s[j];
                qArr[wave][j * 16 + l15] = q[j];
            }
        }
        __syncthreads();
        if (tid < 128) {
            int half = tid >> 6;
            int cc = tid & 63;
            float ss = sArr[half * 2][cc] + sArr[half * 2 + 1][cc];
            float qq = qArr[half * 2][cc] + qArr[half * 2 + 1][cc];
            int colI = n0 + half * 64 + cc;
            psum[(size_t)colI * chunks + blockIdx.y] = ss;
            psumsq[(size_t)colI * chunks + blockIdx.y] = qq;
        }
    }
}

// ---------------- bf16 gather, C=256 channels, bf16 out ---------------------

__global__ __launch_bounds__(256) void gather_bf_kernel(
    const ushort* __restrict__ xl, const int* __restrict__ rowptr,
    const int* __restrict__ adj, const float* __restrict__ dis,
    ushort* __restrict__ h) {
    int v = blockIdx.x;
    int wave = threadIdx.x >> 6;
    int lane = threadIdx.x & 63;
    float dv = dis[v];

    float acc[4] = {0.f, 0.f, 0.f, 0.f};
    int e0 = rowptr[v], e1 = rowptr[v + 1];
    for (int e = e0 + wave; e < e1; e += 4) {
        int r = adj[e];
        float wgt = dis[r] * dv;
        ushort4 u = ((const ushort4*)xl)[(size_t)r * 64 + lane];
        acc[0] = fmaf(bf2f(u.x), wgt, acc[0]);
        acc[1] = fmaf(bf2f(u.y), wgt, acc[1]);
        acc[2] = fmaf(bf2f(u.z), wgt, acc[2]);
        acc[3] = fmaf(bf2f(u.w), wgt, acc[3]);
    }

    __shared__ float4 red[4][64];
    red[wave][lane] = make_float4(acc[0], acc[1], acc[2], acc[3]);
    __syncthreads();
    if (wave == 0) {
        float4 s = red[0][lane];
        float4 b = red[1][lane];
        float4 c = red[2][lane];
        float4 d = red[3][lane];
        s.x += b.x + c.x + d.x;
        s.y += b.y + c.y + d.y;
        s.z += b.z + c.z + d.z;
        s.w += b.w + c.w + d.w;
        ushort4 u = ((const ushort4*)xl)[(size_t)v * 64 + lane];
        float w2 = dv * dv;
        s.x = fmaf(bf2f(u.x), w2, s.x);
        s.y = fmaf(bf2f(u.y), w2, s.y);
        s.z = fmaf(bf2f(u.z), w2, s.z);
        s.w = fmaf(bf2f(u.w), w2, s.w);
        ushort4 o;
        o.x = f2bf(s.x); o.y = f2bf(s.y); o.z = f2bf(s.z); o.w = f2bf(s.w);
        ((ushort4*)h)[(size_t)v * 64 + lane] = o;
    }
}

// ---------------- BN2 partial stats on bf16 h (channel-major [C][chunks]) ---

__global__ __launch_bounds__(256) void bn_partial_kernel(
    const ushort* __restrict__ h, float* __restrict__ psum, float* __restrict__ psumsq,
    int N, int IC, int rows_per_chunk, int chunks) {
    int groups = IC >> 2;          // 64 for C=256
    int rpi = 256 / groups;        // 4
    int t = threadIdx.x;
    int g = t & (groups - 1);
    int ro = t / groups;
    int r0 = blockIdx.x * rows_per_chunk;
    int r1 = min(r0 + rows_per_chunk, N);

    float4 s = make_float4(0.f, 0.f, 0.f, 0.f);
    float4 q = make_float4(0.f, 0.f, 0.f, 0.f);
    for (int r = r0 + ro; r < r1; r += rpi) {
        ushort4 u = *(const ushort4*)(h + (size_t)r * IC + g * 4);
        float vx = bf2f(u.x), vy = bf2f(u.y), vz = bf2f(u.z), vw = bf2f(u.w);
        s.x += vx; s.y += vy; s.z += vz; s.w += vw;
        q.x += vx * vx; q.y += vy * vy; q.z += vz * vz; q.w += vw * vw;
    }

    __shared__ float4 redS[256];
    __shared__ float4 redQ[256];
    redS[t] = s;
    redQ[t] = q;
    __syncthreads();
    if (ro == 0) {
        for (int i = 1; i < rpi; i++) {
            float4 o = redS[t + i * groups];
            s.x += o.x; s.y += o.y; s.z += o.z; s.w += o.w;
            float4 p = redQ[t + i * groups];
            q.x += p.x; q.y += p.y; q.z += p.z; q.w += p.w;
        }
        int k = blockIdx.x;
        psum[(size_t)(4 * g + 0) * chunks + k] = s.x;
        psum[(size_t)(4 * g + 1) * chunks + k] = s.y;
        psum[(size_t)(4 * g + 2) * chunks + k] = s.z;
        psum[(size_t)(4 * g + 3) * chunks + k] = s.w;
        psumsq[(size_t)(4 * g + 0) * chunks + k] = q.x;
        psumsq[(size_t)(4 * g + 1) * chunks + k] = q.y;
        psumsq[(size_t)(4 * g + 2) * chunks + k] = q.z;
        psumsq[(size_t)(4 * g + 3) * chunks + k] = q.w;
    }
}

// one wave per channel; coalesced lane-parallel reduce -> scale/shift.
__global__ __launch_bounds__(256) void bn_reduce_kernel(
    const float* __restrict__ psum, const float* __restrict__ psumsq,
    const float* __restrict__ gamma, const float* __restrict__ beta,
    float* __restrict__ scale, float* __restrict__ shift,
    int N, int chunks) {
    int wave = threadIdx.x >> 6;
    int lane = threadIdx.x & 63;
    int c = blockIdx.x * 4 + wave;
    float s = 0.f, q = 0.f;
    for (int k = lane; k < chunks; k += 64) {
        s += psum[(size_t)c * chunks + k];
        q += psumsq[(size_t)c * chunks + k];
    }
#pragma unroll
    for (int off = 32; off > 0; off >>= 1) {
        s += __shfl_down(s, off, 64);
        q += __shfl_down(q, off, 64);
    }
    if (lane == 0) {
        float invN = 1.0f / (float)N;
        float mean = s * invN;
        float var = q * invN - mean * mean;
        float sc = gamma[c] * rsqrtf(var + BN_EPS);
        scale[c] = sc;
        shift[c] = beta[c] - mean * sc;
    }
}

// BN+ReLU applied to bf16 h1, bf16 out (feeds GEMM2's A); 8 elems/thread.
__global__ void bn_apply_bb_kernel(const ushort* __restrict__ h,
                                   const float* __restrict__ scale,
                                   const float* __restrict__ shift,
                                   ushort* __restrict__ out, int n8, int IC8) {
    int i = blockIdx.x * blockDim.x + threadIdx.x;
    if (i >= n8) return;
    int c8 = (i & (IC8 - 1)) * 8;
    ushort4 a = ((const ushort4*)h)[2 * i];
    ushort4 b = ((const ushort4*)h)[2 * i + 1];
    ushort4 oa, ob;
    oa.x = f2bf(fmaxf(fmaf(bf2f(a.x), scale[c8 + 0], shift[c8 + 0]), 0.f));
    oa.y = f2bf(fmaxf(fmaf(bf2f(a.y), scale[c8 + 1], shift[c8 + 1]), 0.f));
    oa.z = f2bf(fmaxf(fmaf(bf2f(a.z), scale[c8 + 2], shift[c8 + 2]), 0.f));
    oa.w = f2bf(fmaxf(fmaf(bf2f(a.w), scale[c8 + 3], shift[c8 + 3]), 0.f));
    ob.x = f2bf(fmaxf(fmaf(bf2f(b.x), scale[c8 + 4], shift[c8 + 4]), 0.f));
    ob.y = f2bf(fmaxf(fmaf(bf2f(b.y), scale[c8 + 5], shift[c8 + 5]), 0.f));
    ob.z = f2bf(fmaxf(fmaf(bf2f(b.z), scale[c8 + 6], shift[c8 + 6]), 0.f));
    ob.w = f2bf(fmaxf(fmaf(bf2f(b.w), scale[c8 + 7], shift[c8 + 7]), 0.f));
    ((ushort4*)out)[2 * i] = oa;
    ((ushort4*)out)[2 * i + 1] = ob;
}

// ---------------- final: out = relu(bn2(h2) + x), large grid (bf16 h2) ------

__global__ void final_kernel(const ushort* __restrict__ h2, const float* __restrict__ x,
                             const float* __restrict__ scale, const float* __restrict__ shift,
                             float* __restrict__ out, int total4, int C4) {
    int idx = blockIdx.x * blockDim.x + threadIdx.x;
    if (idx >= total4) return;
    int c4 = (idx & (C4 - 1)) * 4;
    ushort4 u = ((const ushort4*)h2)[idx];
    float4 xv = ((const float4*)x)[idx];
    float4 o;
    o.x = fmaxf(fmaf(bf2f(u.x), scale[c4 + 0], shift[c4 + 0]) + xv.x, 0.f);
    o.y = fmaxf(fmaf(bf2f(u.y), scale[c4 + 1], shift[c4 + 1]) + xv.y, 0.f);
    o.z = fmaxf(fmaf(bf2f(u.z), scale[c4 + 2], shift[c4 + 2]) + xv.z, 0.f);
    o.w = fmaxf(fmaf(bf2f(u.w), scale[c4 + 3], shift[c4 + 3]) + xv.w, 0.f);
    ((float4*)out)[idx] = o;
}

// ---------------- launch ----------------

extern "C" void kernel_launch(void* const* d_in, const int* in_sizes, int n_in,
                              void* d_out, int out_size, void* d_ws, size_t ws_size,
                              hipStream_t stream) {
    const float* x  = (const float*)d_in[0];
    const int*   es = (const int*)d_in[1];
    const float* W1 = (const float*)d_in[2];
    const float* g1 = (const float*)d_in[3];
    const float* b1 = (const float*)d_in[4];
    const float* W2 = (const float*)d_in[5];
    const float* g2 = (const float*)d_in[6];
    const float* b2 = (const float*)d_in[7];
    float* out = (float*)d_out;

    const int E  = in_sizes[1] / 2;
    const int IC = in_sizes[3];   // 512
    const int C  = in_sizes[7];   // 256
    const int N  = in_sizes[0] / C;
    const int MTILES = (N + 127) / 128;   // 79
    const int CHUNKS2 = 512;

    const int* row = es;
    const int* col = es + E;

    // ---- workspace layout (cnt first: single memset) ----
    char* w = (char*)d_ws;
    size_t off = 0;
    auto alloc = [&](size_t bytes) -> void* {
        void* p = w + off;
        off = (off + bytes + 255) & ~(size_t)255;
        return p;
    };
    int*   cnt     = (int*)alloc((size_t)N * 4);
    float* dis     = (float*)alloc((size_t)N * 4);
    int*   rowptr  = (int*)alloc((size_t)(N + 1) * 4);
    int*   cursor  = (int*)alloc((size_t)N * 4);
    int*   adj     = (int*)alloc((size_t)E * 4);
    float* psum1   = (float*)alloc((size_t)IC * MTILES * 4);
    float* psumsq1 = (float*)alloc((size_t)IC * MTILES * 4);
    float* psum2   = (float*)alloc((size_t)C * CHUNKS2 * 4);
    float* psumsq2 = (float*)alloc((size_t)C * CHUNKS2 * 4);
    float* scale1  = (float*)alloc((size_t)IC * 4);
    float* shift1  = (float*)alloc((size_t)IC * 4);
    float* scale2  = (float*)alloc((size_t)C * 4);
    float* shift2  = (float*)alloc((size_t)C * 4);
    ushort* xbf    = (ushort*)alloc((size_t)N * C * 2);
    ushort* W1bf   = (ushort*)alloc((size_t)IC * C * 2);
    ushort* W2bf   = (ushort*)alloc((size_t)IC * C * 2);
    ushort* g1x    = (ushort*)alloc((size_t)N * C * 2);
    ushort* h1raw  = (ushort*)alloc((size_t)N * IC * 2);  // GEMM1 out, bf16
    ushort* h1bf   = (ushort*)alloc((size_t)N * IC * 2);  // BN1+ReLU out
    ushort* xl2bf  = (ushort*)alloc((size_t)N * C * 2);
    ushort* h2     = (ushort*)alloc((size_t)N * C * 2);   // gather2 out, bf16

    hipMemsetAsync(cnt, 0, (size_t)N * 4, stream);

    // ---- prep: degree count + bf16 casts ----
    {
        int n4x = N * C / 4, n4w = IC * C / 4;
        int tot = E + n4x + 2 * n4w;
        prep_kernel<<<(tot + 255) / 256, 256, 0, stream>>>(
            col, cnt, x, W1, W2, xbf, W1bf, W2bf, E, n4x, n4w);
    }
    scan_dis_kernel<<<1, 1024, 0, stream>>>(cnt, dis, rowptr, cursor, N);
    scatter_kernel<<<(E + 255) / 256, 256, 0, stream>>>(row, col, cursor, adj, E);

    // ---- layer 1: g1x = A_norm(x); h1raw = g1x @ W1^T (bf16 + stats1) ----
    gather_bf_kernel<<<N, 256, 0, stream>>>(xbf, rowptr, adj, dis, g1x);
    {
        dim3 grid(IC / 128, MTILES);
        gemm_mfma_kernel<true, true><<<grid, 256, 0, stream>>>(
            g1x, W1bf, h1raw, psum1, psumsq1, MTILES, N, IC, C);
    }
    bn_reduce_kernel<<<IC / 4, 256, 0, stream>>>(psum1, psumsq1, g1, b1, scale1, shift1, N, MTILES);
    bn_apply_bb_kernel<<<((N * IC / 8) + 255) / 256, 256, 0, stream>>>(
        h1raw, scale1, shift1, h1bf, N * IC / 8, IC / 8);

    // ---- layer 2: xl2 = h1bf @ W2^T (bf16 out); h2 = A_norm(xl2) bf16 ----
    {
        dim3 grid(C / 128, MTILES);
        gemm_mfma_kernel<true, false><<<grid, 256, 0, stream>>>(
            h1bf, W2bf, xl2bf, nullptr, nullptr, 0, N, C, IC);
    }
    gather_bf_kernel<<<N, 256, 0, stream>>>(xl2bf, rowptr, adj, dis, h2);
    {
        int rpc = (N + CHUNKS2 - 1) / CHUNKS2;
        bn_partial_kernel<<<CHUNKS2, 256, 0, stream>>>(h2, psum2, psumsq2, N, C, rpc, CHUNKS2);
    }
    bn_reduce_kernel<<<C / 4, 256, 0, stream>>>(psum2, psumsq2, g2, b2, scale2, shift2, N, CHUNKS2);

    // ---- epilogue: relu(bn2(h2) + x), saturating grid ----
    {
        int total4 = (N * C) / 4;
        final_kernel<<<(total4 + 255) / 256, 256, 0, stream>>>(h2, x, scale2, shift2, out, total4, C / 4);
    }
}